// Round 11
// baseline (267.167 us; speedup 1.0000x reference)
//
#include <hip/hip_runtime.h>
#include <math.h>

#define NQC   2048
#define NKVC  2048
#define DIMC  256
#define SCALEF 0.17677669529663687f   // 1/sqrt(32), folded into Q weights in prep

typedef short bfrag __attribute__((ext_vector_type(8)));   // 8 bf16 = 4 VGPRs
typedef float ffrag __attribute__((ext_vector_type(4)));   // MFMA C/D
typedef unsigned short us8 __attribute__((ext_vector_type(8)));

__device__ __forceinline__ float gelu_exact(float x) {
    return 0.5f * x * (1.0f + erff(x * 0.70710678118654752f));
}
__device__ __forceinline__ unsigned short f2bf(float f) {
    union { float f; unsigned u; } v; v.f = f;
    unsigned r = v.u + 0x7FFFu + ((v.u >> 16) & 1u);   // RNE
    return (unsigned short)(r >> 16);
}
__device__ __forceinline__ float bf2f(unsigned short u) {
    union { unsigned u; float f; } v; v.u = ((unsigned)u) << 16;
    return v.f;
}

// ---------------- LN device body (one wave per row) ----------------
__device__ __forceinline__ void ln_row(
    const float* __restrict__ x, const float* __restrict__ g,
    const float* __restrict__ b, unsigned short* __restrict__ y, int row)
{
    int lane = threadIdx.x & 63;
    const float* xr = x + (size_t)row * DIMC + lane * 4;
    float4 vv = *(const float4*)xr;
    float s  = vv.x + vv.y + vv.z + vv.w;
    float sq = vv.x*vv.x + vv.y*vv.y + vv.z*vv.z + vv.w*vv.w;
    #pragma unroll
    for (int off = 32; off >= 1; off >>= 1) {
        s  += __shfl_xor(s, off);
        sq += __shfl_xor(sq, off);
    }
    float mean = s * (1.0f/DIMC);
    float inv  = rsqrtf(sq * (1.0f/DIMC) - mean*mean + 1e-5f);
    float4 gg = *(const float4*)(g + lane*4);
    float4 bb = *(const float4*)(b + lane*4);
    ushort4 o;
    o.x = f2bf((vv.x - mean) * inv * gg.x + bb.x);
    o.y = f2bf((vv.y - mean) * inv * gg.y + bb.y);
    o.z = f2bf((vv.z - mean) * inv * gg.z + bb.z);
    o.w = f2bf((vv.w - mean) * inv * gg.w + bb.w);
    *(ushort4*)(y + (size_t)row * DIMC + lane * 4) = o;
}

// ---------------- packed head-of-stream kernel ----------------
// blocks 0..1535    : weight prep (merge/mergex branches skip k<256 — fold_w owns it)
// blocks 1536..2559 : stage-1 LayerNorm (nq)
// blocks 2560..2591 : fold_w  (Wfold = proj @ merge_top -> WTm[:, k<256], bf16^T)
// blocks 2592..3103 : fold_bias (biasN = merge_b + proj_b @ merge_top)
__global__ __launch_bounds__(256) void prep_ln(
    const float* __restrict__ qkv, const float* __restrict__ knn,
    const float* __restrict__ proj, const float* __restrict__ merge,
    const float* __restrict__ caq, const float* __restrict__ knnx,
    const float* __restrict__ cakv, const float* __restrict__ projx,
    const float* __restrict__ mergex, const float* __restrict__ fc1,
    const float* __restrict__ fc2, unsigned short* __restrict__ dst,
    const float* __restrict__ lx, const float* __restrict__ lg,
    const float* __restrict__ lb, unsigned short* __restrict__ ly,
    const float* __restrict__ pb, const float* __restrict__ mb,
    const float* __restrict__ pbx, const float* __restrict__ mbx,
    float* __restrict__ biasN)
{
    __shared__ float As[16][64];
    __shared__ float Bs[16][64];
    int bx = blockIdx.x;
    if (bx >= 2592) {
        // ---- fold_bias ----
        __shared__ float red[4];
        int bb = bx - 2592;
        int z = bb >> 8, n = bb & 255;
        const float* PB = z ? pbx : pb;
        const float* MW = z ? mergex : merge;     // [512][256], top 256 rows
        const float* MB = z ? mbx : mb;
        int k = threadIdx.x;
        float s = PB[k] * MW[(size_t)k * 256 + n];
        #pragma unroll
        for (int off = 32; off >= 1; off >>= 1) s += __shfl_xor(s, off);
        int wid = threadIdx.x >> 6;
        if ((threadIdx.x & 63) == 0) red[wid] = s;
        __syncthreads();
        if (threadIdx.x == 0)
            biasN[z * 256 + n] = MB[n] + red[0] + red[1] + red[2] + red[3];
        return;
    }
    if (bx >= 2560) {
        // ---- fold_w: D[n][k<256] = (proj @ merge_top)[k][n] ----
        int bb = bx - 2560;
        int fx = bb & 3, fy = (bb >> 2) & 3, fz = bb >> 4;
        const float* A = fz ? projx : proj;        // [256][256]
        const float* B = fz ? mergex : merge;      // [512][256], top rows
        unsigned short* D = dst + (fz ? 917504 : 393216);   // [256][512]
        int tid = threadIdx.x;
        int tx = tid & 15, ty = tid >> 4;
        int row0 = fy * 64, col0 = fx * 64;
        int arow = tid >> 2, acol = (tid & 3) * 4;
        int brow = tid >> 4, bcol = (tid & 15) * 4;
        float acc[4][4] = {};
        for (int j0 = 0; j0 < 256; j0 += 16) {
            __syncthreads();
            float4 av = *(const float4*)(A + (size_t)(row0 + arow) * 256 + j0 + acol);
            float4 bv = *(const float4*)(B + (size_t)(j0 + brow) * 256 + col0 + bcol);
            As[acol+0][arow] = av.x; As[acol+1][arow] = av.y;
            As[acol+2][arow] = av.z; As[acol+3][arow] = av.w;
            *(float4*)&Bs[brow][bcol] = bv;
            __syncthreads();
            #pragma unroll
            for (int j = 0; j < 16; ++j) {
                float4 a4 = *(const float4*)&As[j][ty*4];
                float4 b4 = *(const float4*)&Bs[j][tx*4];
                float ar[4] = {a4.x, a4.y, a4.z, a4.w};
                float br[4] = {b4.x, b4.y, b4.z, b4.w};
                #pragma unroll
                for (int ii = 0; ii < 4; ++ii)
                    #pragma unroll
                    for (int jj = 0; jj < 4; ++jj)
                        acc[ii][jj] = fmaf(ar[ii], br[jj], acc[ii][jj]);
            }
        }
        #pragma unroll
        for (int ii = 0; ii < 4; ++ii)
            #pragma unroll
            for (int jj = 0; jj < 4; ++jj)
                D[(size_t)(col0 + tx*4 + jj) * 512 + row0 + ty*4 + ii] = f2bf(acc[ii][jj]);
        return;
    }
    if (bx >= 1536) {
        int row = (bx - 1536) * 4 + (threadIdx.x >> 6);
        ln_row(lx, lg, lb, ly, row);
        return;
    }
    int e = (bx * 256 + threadIdx.x) * 4;
    float v[4];
    float scale = 1.0f;
    bool skip = false;
    if (e < 327680) {
        int n = e >> 8, k = e & 255;
        if (n < 768) {
            const float* s = qkv + (size_t)k * 768 + n;
            #pragma unroll
            for (int i = 0; i < 4; ++i) v[i] = s[(size_t)i * 768];
            if (n < 256) scale = SCALEF;            // Q columns: fold attention scale
        } else if (n < 1024) {
            const float* s = knn + (size_t)k * 256 + (n - 768);
            #pragma unroll
            for (int i = 0; i < 4; ++i) v[i] = s[(size_t)i * 256];
        } else {
            const float* s = knn + (size_t)k * 256 + (n - 1024);
            #pragma unroll
            for (int i = 0; i < 4; ++i) v[i] = s[65536 + (size_t)i * 256] - s[(size_t)i * 256];
        }
    } else if (e < 393216) {
        int l = e - 327680, n = l >> 8, k = l & 255;
        const float* s = proj + (size_t)k * 256 + n;
        #pragma unroll
        for (int i = 0; i < 4; ++i) v[i] = s[(size_t)i * 256];
    } else if (e < 524288) {
        int l = e - 393216, n = l >> 9, k = l & 511;
        if (k < 256) { skip = true; v[0]=v[1]=v[2]=v[3]=0.f; }  // fold_w owns k<256
        else {
            const float* s = merge + (size_t)k * 256 + n;
            #pragma unroll
            for (int i = 0; i < 4; ++i) v[i] = s[(size_t)i * 256];
        }
    } else if (e < 655360) {
        int l = e - 524288, n = l >> 8, k = l & 255;
        if (n < 256) {
            const float* s = caq + (size_t)k * 256 + n;
            #pragma unroll
            for (int i = 0; i < 4; ++i) v[i] = s[(size_t)i * 256];
            scale = SCALEF;                         // ca_q: fold attention scale
        } else {
            const float* s = knnx + (size_t)k * 256 + (n - 256);
            #pragma unroll
            for (int i = 0; i < 4; ++i) v[i] = s[65536 + (size_t)i * 256] - s[(size_t)i * 256];
        }
    } else if (e < 851968) {
        int l = e - 655360, n = l >> 8, k = l & 255;
        if (n < 512) {
            const float* s = cakv + (size_t)k * 512 + n;
            #pragma unroll
            for (int i = 0; i < 4; ++i) v[i] = s[(size_t)i * 512];
        } else {
            const float* s = knnx + (size_t)k * 256 + (n - 512);
            #pragma unroll
            for (int i = 0; i < 4; ++i) v[i] = s[(size_t)i * 256];
        }
    } else if (e < 917504) {
        int l = e - 851968, n = l >> 8, k = l & 255;
        const float* s = projx + (size_t)k * 256 + n;
        #pragma unroll
        for (int i = 0; i < 4; ++i) v[i] = s[(size_t)i * 256];
    } else if (e < 1048576) {
        int l = e - 917504, n = l >> 9, k = l & 511;
        if (k < 256) { skip = true; v[0]=v[1]=v[2]=v[3]=0.f; }  // fold_w owns k<256
        else {
            const float* s = mergex + (size_t)k * 256 + n;
            #pragma unroll
            for (int i = 0; i < 4; ++i) v[i] = s[(size_t)i * 256];
        }
    } else if (e < 1310720) {
        int l = e - 1048576, n = l >> 8, k = l & 255;
        const float* s = fc1 + (size_t)k * 1024 + n;
        #pragma unroll
        for (int i = 0; i < 4; ++i) v[i] = s[(size_t)i * 1024];
    } else {
        int l = e - 1310720, n = l >> 10, k = l & 1023;
        const float* s = fc2 + (size_t)k * 256 + n;
        #pragma unroll
        for (int i = 0; i < 4; ++i) v[i] = s[(size_t)i * 256];
    }
    if (!skip) {
        ushort4 o;
        o.x = f2bf(v[0] * scale); o.y = f2bf(v[1] * scale);
        o.z = f2bf(v[2] * scale); o.w = f2bf(v[3] * scale);
        *(ushort4*)(dst + e) = o;
    }
}

// ---------------- dual-source LayerNorm (stage 2: nq2 and nv in one dispatch) ----------------
__global__ __launch_bounds__(256) void ln2_b(
    const float* __restrict__ x1, const float* __restrict__ g1,
    const float* __restrict__ b1, unsigned short* __restrict__ y1,
    const float* __restrict__ x2, const float* __restrict__ g2,
    const float* __restrict__ b2, unsigned short* __restrict__ y2)
{
    int wid = threadIdx.x >> 6;
    int blk = blockIdx.x;
    if (blk < 1024) ln_row(x1, g1, b1, y1, blk * 4 + wid);
    else            ln_row(x2, g2, b2, y2, (blk - 1024) * 4 + wid);
}

// ---------------- stage-3 LayerNorm ----------------
__global__ __launch_bounds__(256) void ln_b(
    const float* __restrict__ x, const float* __restrict__ g,
    const float* __restrict__ b, unsigned short* __restrict__ y)
{
    ln_row(x, g, b, y, blockIdx.x * 4 + (threadIdx.x >> 6));
}

// ---------------- bf16 MFMA GEMM, 64x64 tile, BK=64 (bf16 A input) ----------------
template<int ACT, int RESID, int OUTBF>
__global__ __launch_bounds__(256) void gemm64(
    const unsigned short* __restrict__ A, int lda,
    const unsigned short* __restrict__ Wt,
    const float* __restrict__ bias,
    const float* __restrict__ resid, int ldr,
    void* __restrict__ Cp, int ldc, int Kc)
{
    __shared__ unsigned short Alds[64][72];
    __shared__ unsigned short Wlds[64][72];
    const int tid = threadIdx.x;
    const int wid = tid >> 6, lane = tid & 63;
    const int lm = lane & 15, quad = lane >> 4;
    const int wr = wid >> 1, wc = wid & 1;
    const int row0 = blockIdx.y * 64, col0 = blockIdx.x * 64;
    const int ar = tid >> 2, ac = (tid & 3) * 16;
    const unsigned short* Ag = A  + (size_t)(row0 + ar) * lda + ac;
    const unsigned short* Wg = Wt + (size_t)(col0 + ar) * Kc  + ac;

    us8 a0 = *(const us8*)Ag;
    us8 a1 = *(const us8*)(Ag + 8);
    us8 w0 = *(const us8*)Wg;
    us8 w1 = *(const us8*)(Wg + 8);

    ffrag acc[2][2];
    #pragma unroll
    for (int mi = 0; mi < 2; ++mi)
        #pragma unroll
        for (int ni = 0; ni < 2; ++ni)
            acc[mi][ni] = (ffrag){0.f, 0.f, 0.f, 0.f};

    for (int k0 = 0;;) {
        __syncthreads();
        *(us8*)&Alds[ar][ac]   = a0;
        *(us8*)&Alds[ar][ac+8] = a1;
        *(us8*)&Wlds[ar][ac]   = w0;
        *(us8*)&Wlds[ar][ac+8] = w1;
        __syncthreads();
        k0 += 64;
        if (k0 < Kc) {
            a0 = *(const us8*)(Ag + k0);
            a1 = *(const us8*)(Ag + k0 + 8);
            w0 = *(const us8*)(Wg + k0);
            w1 = *(const us8*)(Wg + k0 + 8);
        }
        #pragma unroll
        for (int kc = 0; kc < 2; ++kc) {
            bfrag af[2], bw[2];
            #pragma unroll
            for (int mi = 0; mi < 2; ++mi)
                af[mi] = *(const bfrag*)&Alds[wr*32 + mi*16 + lm][kc*32 + quad*8];
            #pragma unroll
            for (int ni = 0; ni < 2; ++ni)
                bw[ni] = *(const bfrag*)&Wlds[wc*32 + ni*16 + lm][kc*32 + quad*8];
            #pragma unroll
            for (int mi = 0; mi < 2; ++mi)
                #pragma unroll
                for (int ni = 0; ni < 2; ++ni)
                    acc[mi][ni] = __builtin_amdgcn_mfma_f32_16x16x32_bf16(
                        af[mi], bw[ni], acc[mi][ni], 0, 0, 0);
        }
        if (k0 >= Kc) break;
    }
    #pragma unroll
    for (int mi = 0; mi < 2; ++mi) {
        #pragma unroll
        for (int ni = 0; ni < 2; ++ni) {
            int gr = row0 + wr*32 + mi*16 + quad*4;
            int gc = col0 + wc*32 + ni*16 + lm;
            float bv = bias ? bias[gc] : 0.f;
            #pragma unroll
            for (int r = 0; r < 4; ++r) {
                float o = acc[mi][ni][r] + bv;
                if (ACT == 1) o = gelu_exact(o);
                if (RESID) o += resid[(size_t)(gr + r) * ldr + gc];
                if (OUTBF) ((unsigned short*)Cp)[(size_t)(gr + r) * ldc + gc] = f2bf(o);
                else       ((float*)Cp)[(size_t)(gr + r) * ldc + gc] = o;
            }
        }
    }
}

// ---------------- dual-A GEMM: stage-2's two projections in one dispatch ----------------
__global__ __launch_bounds__(256) void gemm64_dual(
    const unsigned short* __restrict__ XB,
    const unsigned short* __restrict__ NVB,
    const unsigned short* __restrict__ WT2,
    const unsigned short* __restrict__ WT3,
    unsigned short* __restrict__ A2,
    unsigned short* __restrict__ A3)
{
    const unsigned short* A; const unsigned short* Wt;
    unsigned short* C; int ldc, col0;
    if (blockIdx.x < 8) { A = XB;  Wt = WT2; C = A2; ldc = 512; col0 = blockIdx.x * 64; }
    else                { A = NVB; Wt = WT3; C = A3; ldc = 768; col0 = (blockIdx.x - 8) * 64; }

    __shared__ unsigned short Alds[64][72];
    __shared__ unsigned short Wlds[64][72];
    const int tid = threadIdx.x;
    const int wid = tid >> 6, lane = tid & 63;
    const int lm = lane & 15, quad = lane >> 4;
    const int wr = wid >> 1, wc = wid & 1;
    const int row0 = blockIdx.y * 64;
    const int ar = tid >> 2, ac = (tid & 3) * 16;
    const unsigned short* Ag = A  + (size_t)(row0 + ar) * 256 + ac;
    const unsigned short* Wg = Wt + (size_t)(col0 + ar) * 256 + ac;

    us8 a0 = *(const us8*)Ag;
    us8 a1 = *(const us8*)(Ag + 8);
    us8 w0 = *(const us8*)Wg;
    us8 w1 = *(const us8*)(Wg + 8);

    ffrag acc[2][2];
    #pragma unroll
    for (int mi = 0; mi < 2; ++mi)
        #pragma unroll
        for (int ni = 0; ni < 2; ++ni)
            acc[mi][ni] = (ffrag){0.f, 0.f, 0.f, 0.f};

    for (int k0 = 0;;) {
        __syncthreads();
        *(us8*)&Alds[ar][ac]   = a0;
        *(us8*)&Alds[ar][ac+8] = a1;
        *(us8*)&Wlds[ar][ac]   = w0;
        *(us8*)&Wlds[ar][ac+8] = w1;
        __syncthreads();
        k0 += 64;
        if (k0 < 256) {
            a0 = *(const us8*)(Ag + k0);
            a1 = *(const us8*)(Ag + k0 + 8);
            w0 = *(const us8*)(Wg + k0);
            w1 = *(const us8*)(Wg + k0 + 8);
        }
        #pragma unroll
        for (int kc = 0; kc < 2; ++kc) {
            bfrag af[2], bw[2];
            #pragma unroll
            for (int mi = 0; mi < 2; ++mi)
                af[mi] = *(const bfrag*)&Alds[wr*32 + mi*16 + lm][kc*32 + quad*8];
            #pragma unroll
            for (int ni = 0; ni < 2; ++ni)
                bw[ni] = *(const bfrag*)&Wlds[wc*32 + ni*16 + lm][kc*32 + quad*8];
            #pragma unroll
            for (int mi = 0; mi < 2; ++mi)
                #pragma unroll
                for (int ni = 0; ni < 2; ++ni)
                    acc[mi][ni] = __builtin_amdgcn_mfma_f32_16x16x32_bf16(
                        af[mi], bw[ni], acc[mi][ni], 0, 0, 0);
        }
        if (k0 >= 256) break;
    }
    #pragma unroll
    for (int mi = 0; mi < 2; ++mi) {
        #pragma unroll
        for (int ni = 0; ni < 2; ++ni) {
            int gr = row0 + wr*32 + mi*16 + quad*4;
            int gc = col0 + wc*32 + ni*16 + lm;
            #pragma unroll
            for (int r = 0; r < 4; ++r)
                C[(size_t)(gr + r) * ldc + gc] = f2bf(acc[mi][ni][r]);
        }
    }
}

// ---------------- merged merge-GEMM, K=512: A = [comb2(Opart) | knn_out] ----------------
__global__ __launch_bounds__(256) void gemm64_mc(
    const unsigned short* __restrict__ Op, const float* __restrict__ Lp,
    const unsigned short* __restrict__ Kn,
    const unsigned short* __restrict__ Wt,
    const float* __restrict__ biasN,
    const float* __restrict__ resid,
    float* __restrict__ Cp)
{
    __shared__ unsigned short Alds[64][72];
    __shared__ unsigned short Wlds[64][72];
    const int tid = threadIdx.x;
    const int wid = tid >> 6, lane = tid & 63;
    const int lm = lane & 15, quad = lane >> 4;
    const int wr = wid >> 1, wc = wid & 1;
    const int row0 = blockIdx.y * 64, col0 = blockIdx.x * 64;
    const int ar = tid >> 2, ac = (tid & 3) * 16;
    const int grow = row0 + ar;
    const unsigned short* O0 = Op + (size_t)grow * 256;
    const unsigned short* O1 = O0 + (size_t)4096 * 256;
    const float* L0 = Lp + (size_t)grow * 8;
    const float* L1 = L0 + (size_t)4096 * 8;
    const unsigned short* Kr = Kn + (size_t)grow * 256;
    const unsigned short* Wg = Wt + (size_t)(col0 + ar) * 512;

    us8 a0, a1, w0, w1;
    auto load_a = [&](int k0, us8& x0, us8& x1) {
        if (k0 < 256) {
            int kk = k0 + ac, hh = kk >> 5;
            float li = 1.0f / (L0[hh] + L1[hh]);
            us8 p00 = *(const us8*)(O0 + kk), p01 = *(const us8*)(O0 + kk + 8);
            us8 p10 = *(const us8*)(O1 + kk), p11 = *(const us8*)(O1 + kk + 8);
            #pragma unroll
            for (int i = 0; i < 8; ++i) {
                x0[i] = f2bf((bf2f(p00[i]) + bf2f(p10[i])) * li);
                x1[i] = f2bf((bf2f(p01[i]) + bf2f(p11[i])) * li);
            }
        } else {
            x0 = *(const us8*)(Kr + k0 - 256 + ac);
            x1 = *(const us8*)(Kr + k0 - 256 + ac + 8);
        }
    };
    load_a(0, a0, a1);
    w0 = *(const us8*)(Wg + ac);
    w1 = *(const us8*)(Wg + ac + 8);

    ffrag acc[2][2];
    #pragma unroll
    for (int mi = 0; mi < 2; ++mi)
        #pragma unroll
        for (int ni = 0; ni < 2; ++ni)
            acc[mi][ni] = (ffrag){0.f, 0.f, 0.f, 0.f};

    for (int k0 = 0;;) {
        __syncthreads();
        *(us8*)&Alds[ar][ac]   = a0;
        *(us8*)&Alds[ar][ac+8] = a1;
        *(us8*)&Wlds[ar][ac]   = w0;
        *(us8*)&Wlds[ar][ac+8] = w1;
        __syncthreads();
        k0 += 64;
        if (k0 < 512) {
            load_a(k0, a0, a1);
            w0 = *(const us8*)(Wg + k0 + ac);
            w1 = *(const us8*)(Wg + k0 + ac + 8);
        }
        #pragma unroll
        for (int kc = 0; kc < 2; ++kc) {
            bfrag af[2], bw[2];
            #pragma unroll
            for (int mi = 0; mi < 2; ++mi)
                af[mi] = *(const bfrag*)&Alds[wr*32 + mi*16 + lm][kc*32 + quad*8];
            #pragma unroll
            for (int ni = 0; ni < 2; ++ni)
                bw[ni] = *(const bfrag*)&Wlds[wc*32 + ni*16 + lm][kc*32 + quad*8];
            #pragma unroll
            for (int mi = 0; mi < 2; ++mi)
                #pragma unroll
                for (int ni = 0; ni < 2; ++ni)
                    acc[mi][ni] = __builtin_amdgcn_mfma_f32_16x16x32_bf16(
                        af[mi], bw[ni], acc[mi][ni], 0, 0, 0);
        }
        if (k0 >= 512) break;
    }
    #pragma unroll
    for (int mi = 0; mi < 2; ++mi) {
        #pragma unroll
        for (int ni = 0; ni < 2; ++ni) {
            int gr = row0 + wr*32 + mi*16 + quad*4;
            int gc = col0 + wc*32 + ni*16 + lm;
            float bv = biasN[gc];
            #pragma unroll
            for (int r = 0; r < 4; ++r) {
                float o = acc[mi][ni][r] + bv + resid[(size_t)(gr + r) * 256 + gc];
                Cp[(size_t)(gr + r) * 256 + gc] = o;
            }
        }
    }
}

// ---------------- packed: flash attention (z<4) + KNN gather (z>=4) ----------------
__global__ __launch_bounds__(256) void attn_gather(
    const unsigned short* __restrict__ Qp, int ldq,
    const unsigned short* __restrict__ Kp, int ldk,
    const unsigned short* __restrict__ Vp, int ldv,
    unsigned short* __restrict__ Op, float* __restrict__ Lp,
    const unsigned short* __restrict__ P, int ldp,
    const unsigned short* __restrict__ Base, int ldb,
    const float* __restrict__ gbias, const int* __restrict__ idx,
    unsigned short* __restrict__ gout, int ldgo)
{
    __shared__ unsigned short Klds[64][40];
    __shared__ unsigned short Vt[32][72];
    __shared__ unsigned short Plds[4][16][72];
    int tid = threadIdx.x, wid = tid >> 6, lane = tid & 63;

    if (blockIdx.z >= 4) {
        // ---- gather branch ----
        int gbid = blockIdx.x + 32 * (blockIdx.y + 8 * (blockIdx.z - 4));
        int q = gbid * 4 + wid;
        int b = q >> 11;
        int c = lane * 4;
        ushort4 bu = *(const ushort4*)(Base + (size_t)q * ldb + c);
        float4 bi = *(const float4*)(gbias + c);
        float bsx = bf2f(bu.x) + bi.x, bsy = bf2f(bu.y) + bi.y;
        float bsz = bf2f(bu.z) + bi.z, bsw = bf2f(bu.w) + bi.w;
        float4 acc = make_float4(-3e38f, -3e38f, -3e38f, -3e38f);
        const int* ip = idx + (size_t)q * 8;
        #pragma unroll
        for (int k = 0; k < 8; ++k) {
            int j = ip[k];
            ushort4 pu = *(const ushort4*)(P + ((size_t)(b * NKVC + j)) * ldp + c);
            float t;
            t = bsx + bf2f(pu.x); t = t > 0.f ? t : 0.2f * t; acc.x = fmaxf(acc.x, t);
            t = bsy + bf2f(pu.y); t = t > 0.f ? t : 0.2f * t; acc.y = fmaxf(acc.y, t);
            t = bsz + bf2f(pu.z); t = t > 0.f ? t : 0.2f * t; acc.z = fmaxf(acc.z, t);
            t = bsw + bf2f(pu.w); t = t > 0.f ? t : 0.2f * t; acc.w = fmaxf(acc.w, t);
        }
        ushort4 o;
        o.x = f2bf(acc.x); o.y = f2bf(acc.y); o.z = f2bf(acc.z); o.w = f2bf(acc.w);
        *(ushort4*)(gout + (size_t)q * ldgo + c) = o;
        return;
    }

    // ---- attention branch (KV-split x2, fixed-max softmax) ----
    int zc = blockIdx.z, bb = zc >> 1, ck = zc & 1;
    int h = blockIdx.y;
    int hoff = h * 32;
    int lm = lane & 15, quad = lane >> 4;
    size_t qbase  = (size_t)bb * NQC;
    size_t kvbase = (size_t)bb * NKVC;
    int q0 = blockIdx.x * 64 + wid * 16;

    bfrag aq = *(const bfrag*)(Qp + (qbase + q0 + lm) * (size_t)ldq + hoff + quad * 8);

    float l_r[4] = {0.f, 0.f, 0.f, 0.f};
    ffrag oacc[2];
    oacc[0] = (ffrag){0.f, 0.f, 0.f, 0.f};
    oacc[1] = (ffrag){0.f, 0.f, 0.f, 0.f};

    const int kkey = tid >> 2, kd0 = (tid & 3) * 8;
    const int vkey = tid & 63, vd0 = (tid >> 6) * 8;
    const unsigned short* kg0 = Kp + (kvbase + kkey) * (size_t)ldk + hoff + kd0;
    const unsigned short* vg0 = Vp + (kvbase + vkey) * (size_t)ldv + hoff + vd0;

    for (int kt = ck * 16; kt < ck * 16 + 16; ++kt) {
        us8 kv = *(const us8*)(kg0 + (size_t)kt * 64 * ldk);
        us8 vv = *(const us8*)(vg0 + (size_t)kt * 64 * ldv);
        __syncthreads();
        *(us8*)&Klds[kkey][kd0] = kv;
        #pragma unroll
        for (int i = 0; i < 8; ++i) Vt[vd0 + i][vkey] = vv[i];
        __syncthreads();

        ffrag sacc[4];
        #pragma unroll
        for (int t = 0; t < 4; ++t) {
            bfrag bk = *(const bfrag*)&Klds[t*16 + lm][quad * 8];
            sacc[t] = __builtin_amdgcn_mfma_f32_16x16x32_bf16(
                aq, bk, (ffrag){0.f,0.f,0.f,0.f}, 0, 0, 0);
        }

        #pragma unroll
        for (int r = 0; r < 4; ++r) {
            float p0 = __expf(sacc[0][r]), p1 = __expf(sacc[1][r]);
            float p2 = __expf(sacc[2][r]), p3 = __expf(sacc[3][r]);
            l_r[r] += (p0 + p1) + (p2 + p3);
            int row = quad * 4 + r;
            Plds[wid][row][lm +  0] = f2bf(p0);
            Plds[wid][row][lm + 16] = f2bf(p1);
            Plds[wid][row][lm + 32] = f2bf(p2);
            Plds[wid][row][lm + 48] = f2bf(p3);
        }
        asm volatile("s_waitcnt lgkmcnt(0)" ::: "memory");  // wave-private P RAW

        #pragma unroll
        for (int kc = 0; kc < 2; ++kc) {
            bfrag ap = *(const bfrag*)&Plds[wid][lm][kc*32 + quad*8];
            #pragma unroll
            for (int nt = 0; nt < 2; ++nt) {
                bfrag bv = *(const bfrag*)&Vt[nt*16 + lm][kc*32 + quad*8];
                oacc[nt] = __builtin_amdgcn_mfma_f32_16x16x32_bf16(
                    ap, bv, oacc[nt], 0, 0, 0);
            }
        }
    }
    #pragma unroll
    for (int nt = 0; nt < 2; ++nt)
        #pragma unroll
        for (int r = 0; r < 4; ++r)
            Op[((size_t)ck * 4096 + qbase + q0 + quad*4 + r) * 256 + hoff + nt*16 + lm]
                = f2bf(oacc[nt][r]);
    #pragma unroll
    for (int r = 0; r < 4; ++r) {
        float l = l_r[r];
        l += __shfl_xor(l, 1);
        l += __shfl_xor(l, 2);
        l += __shfl_xor(l, 4);
        l += __shfl_xor(l, 8);
        if (lm == 0)
            Lp[((size_t)ck * 4096 + qbase + q0 + quad*4 + r) * 8 + h] = l;
    }
}

extern "C" void kernel_launch(void* const* d_in, const int* in_sizes, int n_in,
                              void* d_out, int out_size, void* d_ws, size_t ws_size,
                              hipStream_t stream) {
    const float* q_in   = (const float*)d_in[0];
    const float* v_in   = (const float*)d_in[1];
    const int*   idx_s  = (const int*)d_in[4];
    const int*   idx_x  = (const int*)d_in[5];
    const float* n1g = (const float*)d_in[6],  *n1b = (const float*)d_in[7];
    const float* nqg = (const float*)d_in[8],  *nqb = (const float*)d_in[9];
    const float* nvg = (const float*)d_in[10], *nvb = (const float*)d_in[11];
    const float* n2g = (const float*)d_in[12], *n2b = (const float*)d_in[13];
    const float* sa_qkv_w  = (const float*)d_in[14];
    const float* sa_proj_w = (const float*)d_in[15];
    const float* sa_proj_b = (const float*)d_in[16];
    const float* ca_q_w    = (const float*)d_in[17];
    const float* ca_kv_w   = (const float*)d_in[18];
    const float* ca_proj_w = (const float*)d_in[19];
    const float* ca_proj_b = (const float*)d_in[20];
    const float* fc1_w = (const float*)d_in[21], *fc1_b = (const float*)d_in[22];
    const float* fc2_w = (const float*)d_in[23], *fc2_b = (const float*)d_in[24];
    const float* knn_w   = (const float*)d_in[25], *knn_b   = (const float*)d_in[26];
    const float* merge_w = (const float*)d_in[27], *merge_b = (const float*)d_in[28];
    const float* knnx_w  = (const float*)d_in[29], *knnx_b  = (const float*)d_in[30];
    const float* mergex_w = (const float*)d_in[31], *mergex_b = (const float*)d_in[32];
    float* out = (float*)d_out;

    unsigned short* A1      = (unsigned short*)d_ws;           // 4096x1280 bf16
    unsigned short* A2      = A1;                              // 4096x512 (stage2 overlay)
    unsigned short* A3      = A1 + (size_t)4096 * 512;         // 4096x768 (stage2 overlay)
    unsigned short* Hb      = A1;                              // 4096x1024 (stage3 overlay)
    unsigned short* KN      = A1 + (size_t)4096 * 1280;        // 4096x256 knn_out
    unsigned short* XB      = KN + (size_t)4096 * 256;         // 4096x256 LN out
    unsigned short* NVB     = XB + (size_t)4096 * 256;         // 4096x256 LN(v)
    unsigned short* WT      = NVB + (size_t)4096 * 256;        // weights, 1572864 us
    unsigned short* WT1     = WT;
    unsigned short* WTmerge = WT + 393216;
    unsigned short* WT2     = WT + 524288;
    unsigned short* WT3     = WT + 655360;
    unsigned short* WTmergex= WT + 917504;
    unsigned short* WTfc1   = WT + 1048576;
    unsigned short* WTfc2   = WT + 1310720;
    unsigned short* Opart   = WT + 1572864;                    // [2][4096][256] bf16
    float* Lpart = (float*)(Opart + (size_t)2 * 4096 * 256);   // [2][4096][8]  f32
    float* biasN = Lpart + (size_t)2 * 4096 * 8;               // [2][256]      f32

    dim3 blk(256);
    dim3 gAG(NQC / 64, 8, 8);     // z<4: attn (b*2+ck); z>=4: gather

    prep_ln<<<dim3(3104), blk, 0, stream>>>(sa_qkv_w, knn_w, sa_proj_w, merge_w,
        ca_q_w, knnx_w, ca_kv_w, ca_proj_w, mergex_w, fc1_w, fc2_w, WT,
        q_in, n1g, n1b, XB,
        sa_proj_b, merge_b, ca_proj_b, mergex_b, biasN);

    // ---- stage 1 ----
    gemm64<0,0,1><<<dim3(20,64), blk, 0, stream>>>(XB, 256, WT1,
        nullptr, nullptr, 0, A1, 1280, 256);                                        // [qkv|P|Base]
    attn_gather<<<gAG, blk, 0, stream>>>(A1, 1280, A1+256, 1280, A1+512, 1280,
        Opart, Lpart, A1+768, 1280, A1+1024, 1280, knn_b, idx_s, KN, 256);
    gemm64_mc<<<dim3(4,64), blk, 0, stream>>>(Opart, Lpart, KN, WTmerge,
        biasN, q_in, out);                                                          // q = q + merge(attn|knn)

    // ---- stage 2 ----
    ln2_b<<<dim3(2048), blk, 0, stream>>>(out, nqg, nqb, XB,
        v_in, nvg, nvb, NVB);                                                       // nq2 + nv
    gemm64_dual<<<dim3(20,64), blk, 0, stream>>>(XB, NVB, WT2, WT3, A2, A3);        // both projections
    attn_gather<<<gAG, blk, 0, stream>>>(A2, 512, A3, 768, A3+256, 768,
        Opart, Lpart, A3+512, 768, A2+256, 512, knnx_b, idx_x, KN, 256);
    gemm64_mc<<<dim3(4,64), blk, 0, stream>>>(Opart, Lpart, KN, WTmergex,
        biasN + 256, out, out);                                                     // q = q + mergex

    // ---- stage 3 ----
    ln_b<<<dim3(1024), blk, 0, stream>>>(out, n2g, n2b, XB);                        // h = LN(q)
    gemm64<1,0,1><<<dim3(16,64), blk, 0, stream>>>(XB, 256, WTfc1,
        fc1_b, nullptr, 0, Hb, 1024, 256);                                          // gelu(LN(q)@fc1+b)
    gemm64<0,1,0><<<dim3(4,64), blk, 0, stream>>>(Hb, 1024, WTfc2,
        fc2_b, out, 256, out, 256, 1024);                                           // q += fc2
}

// Round 12
// 258.502 us; speedup vs baseline: 1.0335x; 1.0335x over previous
//
#include <hip/hip_runtime.h>
#include <math.h>

#define NQC   2048
#define NKVC  2048
#define DIMC  256
#define SCALEF 0.17677669529663687f   // 1/sqrt(32), folded into Q weights in prep

typedef short bfrag __attribute__((ext_vector_type(8)));   // 8 bf16 = 4 VGPRs
typedef float ffrag __attribute__((ext_vector_type(4)));   // MFMA C/D
typedef unsigned short us8 __attribute__((ext_vector_type(8)));

__device__ __forceinline__ float gelu_exact(float x) {
    return 0.5f * x * (1.0f + erff(x * 0.70710678118654752f));
}
__device__ __forceinline__ unsigned short f2bf(float f) {
    union { float f; unsigned u; } v; v.f = f;
    unsigned r = v.u + 0x7FFFu + ((v.u >> 16) & 1u);   // RNE
    return (unsigned short)(r >> 16);
}
__device__ __forceinline__ float bf2f(unsigned short u) {
    union { unsigned u; float f; } v; v.u = ((unsigned)u) << 16;
    return v.f;
}

// ---------------- LN device body (one wave per row) ----------------
__device__ __forceinline__ void ln_row(
    const float* __restrict__ x, const float* __restrict__ g,
    const float* __restrict__ b, unsigned short* __restrict__ y, int row)
{
    int lane = threadIdx.x & 63;
    const float* xr = x + (size_t)row * DIMC + lane * 4;
    float4 vv = *(const float4*)xr;
    float s  = vv.x + vv.y + vv.z + vv.w;
    float sq = vv.x*vv.x + vv.y*vv.y + vv.z*vv.z + vv.w*vv.w;
    #pragma unroll
    for (int off = 32; off >= 1; off >>= 1) {
        s  += __shfl_xor(s, off);
        sq += __shfl_xor(sq, off);
    }
    float mean = s * (1.0f/DIMC);
    float inv  = rsqrtf(sq * (1.0f/DIMC) - mean*mean + 1e-5f);
    float4 gg = *(const float4*)(g + lane*4);
    float4 bb = *(const float4*)(b + lane*4);
    ushort4 o;
    o.x = f2bf((vv.x - mean) * inv * gg.x + bb.x);
    o.y = f2bf((vv.y - mean) * inv * gg.y + bb.y);
    o.z = f2bf((vv.z - mean) * inv * gg.z + bb.z);
    o.w = f2bf((vv.w - mean) * inv * gg.w + bb.w);
    *(ushort4*)(y + (size_t)row * DIMC + lane * 4) = o;
}

// ---------------- packed: weight prep (blocks 0..1535) + stage-1 LN (1536..2559) ----------------
// WT regions (bf16 [N][K]): WT1[1280][256]@0  WTproj[256][256]@327680
// WTmerge[256][512]@393216  WT2[512][256]@524288  WT3[768][256]@655360
// WTprojx[256][256]@851968  WTmergex[256][512]@917504
// WTfc1[1024][256]@1048576  WTfc2[256][1024]@1310720
__global__ __launch_bounds__(256) void prep_ln(
    const float* __restrict__ qkv, const float* __restrict__ knn,
    const float* __restrict__ proj, const float* __restrict__ merge,
    const float* __restrict__ caq, const float* __restrict__ knnx,
    const float* __restrict__ cakv, const float* __restrict__ projx,
    const float* __restrict__ mergex, const float* __restrict__ fc1,
    const float* __restrict__ fc2, unsigned short* __restrict__ dst,
    const float* __restrict__ lx, const float* __restrict__ lg,
    const float* __restrict__ lb, unsigned short* __restrict__ ly)
{
    if (blockIdx.x >= 1536) {
        int row = (blockIdx.x - 1536) * 4 + (threadIdx.x >> 6);
        ln_row(lx, lg, lb, ly, row);
        return;
    }
    int e = (blockIdx.x * 256 + threadIdx.x) * 4;
    float v[4];
    float scale = 1.0f;
    if (e < 327680) {
        int n = e >> 8, k = e & 255;
        if (n < 768) {
            const float* s = qkv + (size_t)k * 768 + n;
            #pragma unroll
            for (int i = 0; i < 4; ++i) v[i] = s[(size_t)i * 768];
            if (n < 256) scale = SCALEF;            // Q columns: fold attention scale
        } else if (n < 1024) {
            const float* s = knn + (size_t)k * 256 + (n - 768);
            #pragma unroll
            for (int i = 0; i < 4; ++i) v[i] = s[(size_t)i * 256];
        } else {
            const float* s = knn + (size_t)k * 256 + (n - 1024);
            #pragma unroll
            for (int i = 0; i < 4; ++i) v[i] = s[65536 + (size_t)i * 256] - s[(size_t)i * 256];
        }
    } else if (e < 393216) {
        int l = e - 327680, n = l >> 8, k = l & 255;
        const float* s = proj + (size_t)k * 256 + n;
        #pragma unroll
        for (int i = 0; i < 4; ++i) v[i] = s[(size_t)i * 256];
    } else if (e < 524288) {
        int l = e - 393216, n = l >> 9, k = l & 511;
        const float* s = merge + (size_t)k * 256 + n;
        #pragma unroll
        for (int i = 0; i < 4; ++i) v[i] = s[(size_t)i * 256];
    } else if (e < 655360) {
        int l = e - 524288, n = l >> 8, k = l & 255;
        if (n < 256) {
            const float* s = caq + (size_t)k * 256 + n;
            #pragma unroll
            for (int i = 0; i < 4; ++i) v[i] = s[(size_t)i * 256];
            scale = SCALEF;                         // ca_q: fold attention scale
        } else {
            const float* s = knnx + (size_t)k * 256 + (n - 256);
            #pragma unroll
            for (int i = 0; i < 4; ++i) v[i] = s[65536 + (size_t)i * 256] - s[(size_t)i * 256];
        }
    } else if (e < 851968) {
        int l = e - 655360, n = l >> 8, k = l & 255;
        if (n < 512) {
            const float* s = cakv + (size_t)k * 512 + n;
            #pragma unroll
            for (int i = 0; i < 4; ++i) v[i] = s[(size_t)i * 512];
        } else {
            const float* s = knnx + (size_t)k * 256 + (n - 512);
            #pragma unroll
            for (int i = 0; i < 4; ++i) v[i] = s[(size_t)i * 256];
        }
    } else if (e < 917504) {
        int l = e - 851968, n = l >> 8, k = l & 255;
        const float* s = projx + (size_t)k * 256 + n;
        #pragma unroll
        for (int i = 0; i < 4; ++i) v[i] = s[(size_t)i * 256];
    } else if (e < 1048576) {
        int l = e - 917504, n = l >> 9, k = l & 511;
        const float* s = mergex + (size_t)k * 256 + n;
        #pragma unroll
        for (int i = 0; i < 4; ++i) v[i] = s[(size_t)i * 256];
    } else if (e < 1310720) {
        int l = e - 1048576, n = l >> 8, k = l & 255;
        const float* s = fc1 + (size_t)k * 1024 + n;
        #pragma unroll
        for (int i = 0; i < 4; ++i) v[i] = s[(size_t)i * 1024];
    } else {
        int l = e - 1310720, n = l >> 10, k = l & 1023;
        const float* s = fc2 + (size_t)k * 256 + n;
        #pragma unroll
        for (int i = 0; i < 4; ++i) v[i] = s[(size_t)i * 256];
    }
    ushort4 o;
    o.x = f2bf(v[0] * scale); o.y = f2bf(v[1] * scale);
    o.z = f2bf(v[2] * scale); o.w = f2bf(v[3] * scale);
    *(ushort4*)(dst + e) = o;
}

// ---------------- dual-source LayerNorm (stage 2: nq2 and nv in one dispatch) ----------------
__global__ __launch_bounds__(256) void ln2_b(
    const float* __restrict__ x1, const float* __restrict__ g1,
    const float* __restrict__ b1, unsigned short* __restrict__ y1,
    const float* __restrict__ x2, const float* __restrict__ g2,
    const float* __restrict__ b2, unsigned short* __restrict__ y2)
{
    int wid = threadIdx.x >> 6;
    int blk = blockIdx.x;
    if (blk < 1024) ln_row(x1, g1, b1, y1, blk * 4 + wid);
    else            ln_row(x2, g2, b2, y2, (blk - 1024) * 4 + wid);
}

// ---------------- stage-3 LayerNorm ----------------
__global__ __launch_bounds__(256) void ln_b(
    const float* __restrict__ x, const float* __restrict__ g,
    const float* __restrict__ b, unsigned short* __restrict__ y)
{
    ln_row(x, g, b, y, blockIdx.x * 4 + (threadIdx.x >> 6));
}

// ---------------- bf16 MFMA GEMM, 64x64 tile, BK=64 (bf16 A input) ----------------
template<int ACT, int RESID, int OUTBF>
__global__ __launch_bounds__(256) void gemm64(
    const unsigned short* __restrict__ A, int lda,
    const unsigned short* __restrict__ Wt,
    const float* __restrict__ bias,
    const float* __restrict__ resid, int ldr,
    void* __restrict__ Cp, int ldc, int Kc)
{
    __shared__ unsigned short Alds[64][72];
    __shared__ unsigned short Wlds[64][72];
    const int tid = threadIdx.x;
    const int wid = tid >> 6, lane = tid & 63;
    const int lm = lane & 15, quad = lane >> 4;
    const int wr = wid >> 1, wc = wid & 1;
    const int row0 = blockIdx.y * 64, col0 = blockIdx.x * 64;
    const int ar = tid >> 2, ac = (tid & 3) * 16;
    const unsigned short* Ag = A  + (size_t)(row0 + ar) * lda + ac;
    const unsigned short* Wg = Wt + (size_t)(col0 + ar) * Kc  + ac;

    us8 a0 = *(const us8*)Ag;
    us8 a1 = *(const us8*)(Ag + 8);
    us8 w0 = *(const us8*)Wg;
    us8 w1 = *(const us8*)(Wg + 8);

    ffrag acc[2][2];
    #pragma unroll
    for (int mi = 0; mi < 2; ++mi)
        #pragma unroll
        for (int ni = 0; ni < 2; ++ni)
            acc[mi][ni] = (ffrag){0.f, 0.f, 0.f, 0.f};

    for (int k0 = 0;;) {
        __syncthreads();
        *(us8*)&Alds[ar][ac]   = a0;
        *(us8*)&Alds[ar][ac+8] = a1;
        *(us8*)&Wlds[ar][ac]   = w0;
        *(us8*)&Wlds[ar][ac+8] = w1;
        __syncthreads();
        k0 += 64;
        if (k0 < Kc) {
            a0 = *(const us8*)(Ag + k0);
            a1 = *(const us8*)(Ag + k0 + 8);
            w0 = *(const us8*)(Wg + k0);
            w1 = *(const us8*)(Wg + k0 + 8);
        }
        #pragma unroll
        for (int kc = 0; kc < 2; ++kc) {
            bfrag af[2], bw[2];
            #pragma unroll
            for (int mi = 0; mi < 2; ++mi)
                af[mi] = *(const bfrag*)&Alds[wr*32 + mi*16 + lm][kc*32 + quad*8];
            #pragma unroll
            for (int ni = 0; ni < 2; ++ni)
                bw[ni] = *(const bfrag*)&Wlds[wc*32 + ni*16 + lm][kc*32 + quad*8];
            #pragma unroll
            for (int mi = 0; mi < 2; ++mi)
                #pragma unroll
                for (int ni = 0; ni < 2; ++ni)
                    acc[mi][ni] = __builtin_amdgcn_mfma_f32_16x16x32_bf16(
                        af[mi], bw[ni], acc[mi][ni], 0, 0, 0);
        }
        if (k0 >= Kc) break;
    }
    #pragma unroll
    for (int mi = 0; mi < 2; ++mi) {
        #pragma unroll
        for (int ni = 0; ni < 2; ++ni) {
            int gr = row0 + wr*32 + mi*16 + quad*4;
            int gc = col0 + wc*32 + ni*16 + lm;
            float bv = bias ? bias[gc] : 0.f;
            #pragma unroll
            for (int r = 0; r < 4; ++r) {
                float o = acc[mi][ni][r] + bv;
                if (ACT == 1) o = gelu_exact(o);
                if (RESID) o += resid[(size_t)(gr + r) * ldr + gc];
                if (OUTBF) ((unsigned short*)Cp)[(size_t)(gr + r) * ldc + gc] = f2bf(o);
                else       ((float*)Cp)[(size_t)(gr + r) * ldc + gc] = o;
            }
        }
    }
}

// ---------------- split-K 8-wave GEMM, 64x64 tile, 512 threads ----------------
// Wave-groups 0/1 each process half of K with private LDS stages (aligned
// barriers: equal trip counts), then group 1 dumps its fp32 partial via LDS
// and group 0 reduces + applies the epilogue. For the 256-block GEMMs
// (merge K=512, fc2 K=1024) this doubles waves/CU and halves the K-chain.
template<int ACT, int RESID, int OUTBF>
__global__ __launch_bounds__(512) void gemm64x8(
    const unsigned short* __restrict__ A, int lda,
    const unsigned short* __restrict__ Wt,
    const float* __restrict__ bias,
    const float* __restrict__ resid, int ldr,
    void* __restrict__ Cp, int ldc, int Kc)
{
    __shared__ unsigned short Alds[2][64][72];
    __shared__ unsigned short Wlds[2][64][72];
    __shared__ float Red[64][68];
    const int tid = threadIdx.x;
    const int g = tid >> 8;                 // K-group
    const int t = tid & 255;
    const int wid2 = (tid >> 6) & 3, lane = tid & 63;
    const int lm = lane & 15, quad = lane >> 4;
    const int wr = wid2 >> 1, wc = wid2 & 1;
    const int row0 = blockIdx.y * 64, col0 = blockIdx.x * 64;
    const int ar = t >> 2, ac = (t & 3) * 16;
    const int KH = Kc >> 1;
    const unsigned short* Ag = A  + (size_t)(row0 + ar) * lda + g * KH + ac;
    const unsigned short* Wg = Wt + (size_t)(col0 + ar) * Kc  + g * KH + ac;

    us8 a0 = *(const us8*)Ag;
    us8 a1 = *(const us8*)(Ag + 8);
    us8 w0 = *(const us8*)Wg;
    us8 w1 = *(const us8*)(Wg + 8);

    ffrag acc[2][2];
    #pragma unroll
    for (int mi = 0; mi < 2; ++mi)
        #pragma unroll
        for (int ni = 0; ni < 2; ++ni)
            acc[mi][ni] = (ffrag){0.f, 0.f, 0.f, 0.f};

    for (int k0 = 0;;) {
        __syncthreads();
        *(us8*)&Alds[g][ar][ac]   = a0;
        *(us8*)&Alds[g][ar][ac+8] = a1;
        *(us8*)&Wlds[g][ar][ac]   = w0;
        *(us8*)&Wlds[g][ar][ac+8] = w1;
        __syncthreads();
        k0 += 64;
        if (k0 < KH) {
            a0 = *(const us8*)(Ag + k0);
            a1 = *(const us8*)(Ag + k0 + 8);
            w0 = *(const us8*)(Wg + k0);
            w1 = *(const us8*)(Wg + k0 + 8);
        }
        #pragma unroll
        for (int kc = 0; kc < 2; ++kc) {
            bfrag af[2], bw[2];
            #pragma unroll
            for (int mi = 0; mi < 2; ++mi)
                af[mi] = *(const bfrag*)&Alds[g][wr*32 + mi*16 + lm][kc*32 + quad*8];
            #pragma unroll
            for (int ni = 0; ni < 2; ++ni)
                bw[ni] = *(const bfrag*)&Wlds[g][wc*32 + ni*16 + lm][kc*32 + quad*8];
            #pragma unroll
            for (int mi = 0; mi < 2; ++mi)
                #pragma unroll
                for (int ni = 0; ni < 2; ++ni)
                    acc[mi][ni] = __builtin_amdgcn_mfma_f32_16x16x32_bf16(
                        af[mi], bw[ni], acc[mi][ni], 0, 0, 0);
        }
        if (k0 >= KH) break;
    }
    // cross-group reduction: group 1 dumps, group 0 adds + epilogue
    __syncthreads();
    if (g == 1) {
        #pragma unroll
        for (int mi = 0; mi < 2; ++mi)
            #pragma unroll
            for (int ni = 0; ni < 2; ++ni) {
                int lr = wr*32 + mi*16 + quad*4;
                int lc = wc*32 + ni*16 + lm;
                #pragma unroll
                for (int r = 0; r < 4; ++r)
                    Red[lr + r][lc] = acc[mi][ni][r];
            }
    }
    __syncthreads();
    if (g == 0) {
        #pragma unroll
        for (int mi = 0; mi < 2; ++mi) {
            #pragma unroll
            for (int ni = 0; ni < 2; ++ni) {
                int lr = wr*32 + mi*16 + quad*4;
                int lc = wc*32 + ni*16 + lm;
                int gr = row0 + lr;
                int gc = col0 + lc;
                float bv = bias ? bias[gc] : 0.f;
                #pragma unroll
                for (int r = 0; r < 4; ++r) {
                    float o = acc[mi][ni][r] + Red[lr + r][lc] + bv;
                    if (ACT == 1) o = gelu_exact(o);
                    if (RESID) o += resid[(size_t)(gr + r) * ldr + gc];
                    if (OUTBF) ((unsigned short*)Cp)[(size_t)(gr + r) * ldc + gc] = f2bf(o);
                    else       ((float*)Cp)[(size_t)(gr + r) * ldc + gc] = o;
                }
            }
        }
    }
}

// ---------------- dual-A GEMM: stage-2's two projections in one dispatch ----------------
__global__ __launch_bounds__(256) void gemm64_dual(
    const unsigned short* __restrict__ XB,
    const unsigned short* __restrict__ NVB,
    const unsigned short* __restrict__ WT2,
    const unsigned short* __restrict__ WT3,
    unsigned short* __restrict__ A2,
    unsigned short* __restrict__ A3)
{
    const unsigned short* A; const unsigned short* Wt;
    unsigned short* C; int ldc, col0;
    if (blockIdx.x < 8) { A = XB;  Wt = WT2; C = A2; ldc = 512; col0 = blockIdx.x * 64; }
    else                { A = NVB; Wt = WT3; C = A3; ldc = 768; col0 = (blockIdx.x - 8) * 64; }

    __shared__ unsigned short Alds[64][72];
    __shared__ unsigned short Wlds[64][72];
    const int tid = threadIdx.x;
    const int wid = tid >> 6, lane = tid & 63;
    const int lm = lane & 15, quad = lane >> 4;
    const int wr = wid >> 1, wc = wid & 1;
    const int row0 = blockIdx.y * 64;
    const int ar = tid >> 2, ac = (tid & 3) * 16;
    const unsigned short* Ag = A  + (size_t)(row0 + ar) * 256 + ac;
    const unsigned short* Wg = Wt + (size_t)(col0 + ar) * 256 + ac;

    us8 a0 = *(const us8*)Ag;
    us8 a1 = *(const us8*)(Ag + 8);
    us8 w0 = *(const us8*)Wg;
    us8 w1 = *(const us8*)(Wg + 8);

    ffrag acc[2][2];
    #pragma unroll
    for (int mi = 0; mi < 2; ++mi)
        #pragma unroll
        for (int ni = 0; ni < 2; ++ni)
            acc[mi][ni] = (ffrag){0.f, 0.f, 0.f, 0.f};

    for (int k0 = 0;;) {
        __syncthreads();
        *(us8*)&Alds[ar][ac]   = a0;
        *(us8*)&Alds[ar][ac+8] = a1;
        *(us8*)&Wlds[ar][ac]   = w0;
        *(us8*)&Wlds[ar][ac+8] = w1;
        __syncthreads();
        k0 += 64;
        if (k0 < 256) {
            a0 = *(const us8*)(Ag + k0);
            a1 = *(const us8*)(Ag + k0 + 8);
            w0 = *(const us8*)(Wg + k0);
            w1 = *(const us8*)(Wg + k0 + 8);
        }
        #pragma unroll
        for (int kc = 0; kc < 2; ++kc) {
            bfrag af[2], bw[2];
            #pragma unroll
            for (int mi = 0; mi < 2; ++mi)
                af[mi] = *(const bfrag*)&Alds[wr*32 + mi*16 + lm][kc*32 + quad*8];
            #pragma unroll
            for (int ni = 0; ni < 2; ++ni)
                bw[ni] = *(const bfrag*)&Wlds[wc*32 + ni*16 + lm][kc*32 + quad*8];
            #pragma unroll
            for (int mi = 0; mi < 2; ++mi)
                #pragma unroll
                for (int ni = 0; ni < 2; ++ni)
                    acc[mi][ni] = __builtin_amdgcn_mfma_f32_16x16x32_bf16(
                        af[mi], bw[ni], acc[mi][ni], 0, 0, 0);
        }
        if (k0 >= 256) break;
    }
    #pragma unroll
    for (int mi = 0; mi < 2; ++mi) {
        #pragma unroll
        for (int ni = 0; ni < 2; ++ni) {
            int gr = row0 + wr*32 + mi*16 + quad*4;
            int gc = col0 + wc*32 + ni*16 + lm;
            #pragma unroll
            for (int r = 0; r < 4; ++r)
                C[(size_t)(gr + r) * ldc + gc] = f2bf(acc[mi][ni][r]);
        }
    }
}

// ---------------- proj GEMM with fused KV-split combine on the A-path ----------------
__global__ __launch_bounds__(256) void gemm64_comb(
    const unsigned short* __restrict__ Op, const float* __restrict__ Lp,
    const unsigned short* __restrict__ Wt,
    const float* __restrict__ bias,
    unsigned short* __restrict__ C, int ldc)
{
    __shared__ unsigned short Alds[64][72];
    __shared__ unsigned short Wlds[64][72];
    const int tid = threadIdx.x;
    const int wid = tid >> 6, lane = tid & 63;
    const int lm = lane & 15, quad = lane >> 4;
    const int wr = wid >> 1, wc = wid & 1;
    const int row0 = blockIdx.y * 64, col0 = blockIdx.x * 64;
    const int ar = tid >> 2, ac = (tid & 3) * 16;
    const int grow = row0 + ar;
    const unsigned short* O0 = Op + (size_t)grow * 256 + ac;
    const unsigned short* O1 = Op + (size_t)(4096 + grow) * 256 + ac;
    const float* L0 = Lp + (size_t)grow * 8;
    const float* L1 = Lp + (size_t)(4096 + grow) * 8;
    const unsigned short* Wg = Wt + (size_t)(col0 + ar) * 256 + ac;

    us8 o00 = *(const us8*)O0;
    us8 o01 = *(const us8*)(O0 + 8);
    us8 o10 = *(const us8*)O1;
    us8 o11 = *(const us8*)(O1 + 8);
    float li = 1.0f / (L0[ac >> 5] + L1[ac >> 5]);
    us8 w0 = *(const us8*)Wg;
    us8 w1 = *(const us8*)(Wg + 8);

    ffrag acc[2][2];
    #pragma unroll
    for (int mi = 0; mi < 2; ++mi)
        #pragma unroll
        for (int ni = 0; ni < 2; ++ni)
            acc[mi][ni] = (ffrag){0.f, 0.f, 0.f, 0.f};

    for (int k0 = 0;;) {
        us8 ac0, ac1;
        #pragma unroll
        for (int i = 0; i < 8; ++i) {
            ac0[i] = f2bf((bf2f(o00[i]) + bf2f(o10[i])) * li);
            ac1[i] = f2bf((bf2f(o01[i]) + bf2f(o11[i])) * li);
        }
        __syncthreads();
        *(us8*)&Alds[ar][ac]   = ac0;
        *(us8*)&Alds[ar][ac+8] = ac1;
        *(us8*)&Wlds[ar][ac]   = w0;
        *(us8*)&Wlds[ar][ac+8] = w1;
        __syncthreads();
        k0 += 64;
        if (k0 < 256) {
            o00 = *(const us8*)(O0 + k0);
            o01 = *(const us8*)(O0 + k0 + 8);
            o10 = *(const us8*)(O1 + k0);
            o11 = *(const us8*)(O1 + k0 + 8);
            li = 1.0f / (L0[(k0 + ac) >> 5] + L1[(k0 + ac) >> 5]);
            w0 = *(const us8*)(Wg + k0);
            w1 = *(const us8*)(Wg + k0 + 8);
        }
        #pragma unroll
        for (int kc = 0; kc < 2; ++kc) {
            bfrag af[2], bw[2];
            #pragma unroll
            for (int mi = 0; mi < 2; ++mi)
                af[mi] = *(const bfrag*)&Alds[wr*32 + mi*16 + lm][kc*32 + quad*8];
            #pragma unroll
            for (int ni = 0; ni < 2; ++ni)
                bw[ni] = *(const bfrag*)&Wlds[wc*32 + ni*16 + lm][kc*32 + quad*8];
            #pragma unroll
            for (int mi = 0; mi < 2; ++mi)
                #pragma unroll
                for (int ni = 0; ni < 2; ++ni)
                    acc[mi][ni] = __builtin_amdgcn_mfma_f32_16x16x32_bf16(
                        af[mi], bw[ni], acc[mi][ni], 0, 0, 0);
        }
        if (k0 >= 256) break;
    }
    #pragma unroll
    for (int mi = 0; mi < 2; ++mi) {
        #pragma unroll
        for (int ni = 0; ni < 2; ++ni) {
            int gr = row0 + wr*32 + mi*16 + quad*4;
            int gc = col0 + wc*32 + ni*16 + lm;
            float bv = bias[gc];
            #pragma unroll
            for (int r = 0; r < 4; ++r)
                C[(size_t)(gr + r) * ldc + gc] = f2bf(acc[mi][ni][r] + bv);
        }
    }
}

// ---------------- packed: flash attention (z<4) + KNN gather (z>=4) ----------------
__global__ __launch_bounds__(256) void attn_gather(
    const unsigned short* __restrict__ Qp, int ldq,
    const unsigned short* __restrict__ Kp, int ldk,
    const unsigned short* __restrict__ Vp, int ldv,
    unsigned short* __restrict__ Op, float* __restrict__ Lp,
    const unsigned short* __restrict__ P, int ldp,
    const unsigned short* __restrict__ Base, int ldb,
    const float* __restrict__ gbias, const int* __restrict__ idx,
    unsigned short* __restrict__ gout, int ldgo)
{
    __shared__ unsigned short Klds[64][40];
    __shared__ unsigned short Vt[32][72];
    __shared__ unsigned short Plds[4][16][72];
    int tid = threadIdx.x, wid = tid >> 6, lane = tid & 63;

    if (blockIdx.z >= 4) {
        // ---- gather branch ----
        int gbid = blockIdx.x + 32 * (blockIdx.y + 8 * (blockIdx.z - 4));
        int q = gbid * 4 + wid;
        int b = q >> 11;
        int c = lane * 4;
        ushort4 bu = *(const ushort4*)(Base + (size_t)q * ldb + c);
        float4 bi = *(const float4*)(gbias + c);
        float bsx = bf2f(bu.x) + bi.x, bsy = bf2f(bu.y) + bi.y;
        float bsz = bf2f(bu.z) + bi.z, bsw = bf2f(bu.w) + bi.w;
        float4 acc = make_float4(-3e38f, -3e38f, -3e38f, -3e38f);
        const int* ip = idx + (size_t)q * 8;
        #pragma unroll
        for (int k = 0; k < 8; ++k) {
            int j = ip[k];
            ushort4 pu = *(const ushort4*)(P + ((size_t)(b * NKVC + j)) * ldp + c);
            float t;
            t = bsx + bf2f(pu.x); t = t > 0.f ? t : 0.2f * t; acc.x = fmaxf(acc.x, t);
            t = bsy + bf2f(pu.y); t = t > 0.f ? t : 0.2f * t; acc.y = fmaxf(acc.y, t);
            t = bsz + bf2f(pu.z); t = t > 0.f ? t : 0.2f * t; acc.z = fmaxf(acc.z, t);
            t = bsw + bf2f(pu.w); t = t > 0.f ? t : 0.2f * t; acc.w = fmaxf(acc.w, t);
        }
        ushort4 o;
        o.x = f2bf(acc.x); o.y = f2bf(acc.y); o.z = f2bf(acc.z); o.w = f2bf(acc.w);
        *(ushort4*)(gout + (size_t)q * ldgo + c) = o;
        return;
    }

    // ---- attention branch (KV-split x2, fixed-max softmax) ----
    int zc = blockIdx.z, bb = zc >> 1, ck = zc & 1;
    int h = blockIdx.y;
    int hoff = h * 32;
    int lm = lane & 15, quad = lane >> 4;
    size_t qbase  = (size_t)bb * NQC;
    size_t kvbase = (size_t)bb * NKVC;
    int q0 = blockIdx.x * 64 + wid * 16;

    bfrag aq = *(const bfrag*)(Qp + (qbase + q0 + lm) * (size_t)ldq + hoff + quad * 8);

    float l_r[4] = {0.f, 0.f, 0.f, 0.f};
    ffrag oacc[2];
    oacc[0] = (ffrag){0.f, 0.f, 0.f, 0.f};
    oacc[1] = (ffrag){0.f, 0.f, 0.f, 0.f};

    const int kkey = tid >> 2, kd0 = (tid & 3) * 8;
    const int vkey = tid & 63, vd0 = (tid >> 6) * 8;
    const unsigned short* kg0 = Kp + (kvbase + kkey) * (size_t)ldk + hoff + kd0;
    const unsigned short* vg0 = Vp + (kvbase + vkey) * (size_t)ldv + hoff + vd0;

    for (int kt = ck * 16; kt < ck * 16 + 16; ++kt) {
        us8 kv = *(const us8*)(kg0 + (size_t)kt * 64 * ldk);
        us8 vv = *(const us8*)(vg0 + (size_t)kt * 64 * ldv);
        __syncthreads();
        *(us8*)&Klds[kkey][kd0] = kv;
        #pragma unroll
        for (int i = 0; i < 8; ++i) Vt[vd0 + i][vkey] = vv[i];
        __syncthreads();

        ffrag sacc[4];
        #pragma unroll
        for (int t = 0; t < 4; ++t) {
            bfrag bk = *(const bfrag*)&Klds[t*16 + lm][quad * 8];
            sacc[t] = __builtin_amdgcn_mfma_f32_16x16x32_bf16(
                aq, bk, (ffrag){0.f,0.f,0.f,0.f}, 0, 0, 0);
        }

        #pragma unroll
        for (int r = 0; r < 4; ++r) {
            float p0 = __expf(sacc[0][r]), p1 = __expf(sacc[1][r]);
            float p2 = __expf(sacc[2][r]), p3 = __expf(sacc[3][r]);
            l_r[r] += (p0 + p1) + (p2 + p3);
            int row = quad * 4 + r;
            Plds[wid][row][lm +  0] = f2bf(p0);
            Plds[wid][row][lm + 16] = f2bf(p1);
            Plds[wid][row][lm + 32] = f2bf(p2);
            Plds[wid][row][lm + 48] = f2bf(p3);
        }
        asm volatile("s_waitcnt lgkmcnt(0)" ::: "memory");  // wave-private P RAW

        #pragma unroll
        for (int kc = 0; kc < 2; ++kc) {
            bfrag ap = *(const bfrag*)&Plds[wid][lm][kc*32 + quad*8];
            #pragma unroll
            for (int nt = 0; nt < 2; ++nt) {
                bfrag bv = *(const bfrag*)&Vt[nt*16 + lm][kc*32 + quad*8];
                oacc[nt] = __builtin_amdgcn_mfma_f32_16x16x32_bf16(
                    ap, bv, oacc[nt], 0, 0, 0);
            }
        }
    }
    #pragma unroll
    for (int nt = 0; nt < 2; ++nt)
        #pragma unroll
        for (int r = 0; r < 4; ++r)
            Op[((size_t)ck * 4096 + qbase + q0 + quad*4 + r) * 256 + hoff + nt*16 + lm]
                = f2bf(oacc[nt][r]);
    #pragma unroll
    for (int r = 0; r < 4; ++r) {
        float l = l_r[r];
        l += __shfl_xor(l, 1);
        l += __shfl_xor(l, 2);
        l += __shfl_xor(l, 4);
        l += __shfl_xor(l, 8);
        if (lm == 0)
            Lp[((size_t)ck * 4096 + qbase + q0 + quad*4 + r) * 8 + h] = l;
    }
}

extern "C" void kernel_launch(void* const* d_in, const int* in_sizes, int n_in,
                              void* d_out, int out_size, void* d_ws, size_t ws_size,
                              hipStream_t stream) {
    const float* q_in   = (const float*)d_in[0];
    const float* v_in   = (const float*)d_in[1];
    const int*   idx_s  = (const int*)d_in[4];
    const int*   idx_x  = (const int*)d_in[5];
    const float* n1g = (const float*)d_in[6],  *n1b = (const float*)d_in[7];
    const float* nqg = (const float*)d_in[8],  *nqb = (const float*)d_in[9];
    const float* nvg = (const float*)d_in[10], *nvb = (const float*)d_in[11];
    const float* n2g = (const float*)d_in[12], *n2b = (const float*)d_in[13];
    const float* sa_qkv_w  = (const float*)d_in[14];
    const float* sa_proj_w = (const float*)d_in[15];
    const float* sa_proj_b = (const float*)d_in[16];
    const float* ca_q_w    = (const float*)d_in[17];
    const float* ca_kv_w   = (const float*)d_in[18];
    const float* ca_proj_w = (const float*)d_in[19];
    const float* ca_proj_b = (const float*)d_in[20];
    const float* fc1_w = (const float*)d_in[21], *fc1_b = (const float*)d_in[22];
    const float* fc2_w = (const float*)d_in[23], *fc2_b = (const float*)d_in[24];
    const float* knn_w   = (const float*)d_in[25], *knn_b   = (const float*)d_in[26];
    const float* merge_w = (const float*)d_in[27], *merge_b = (const float*)d_in[28];
    const float* knnx_w  = (const float*)d_in[29], *knnx_b  = (const float*)d_in[30];
    const float* mergex_w = (const float*)d_in[31], *mergex_b = (const float*)d_in[32];
    float* out = (float*)d_out;

    unsigned short* A1      = (unsigned short*)d_ws;           // 4096x1280 bf16
    unsigned short* A2      = A1;                              // 4096x512 (stage2 overlay)
    unsigned short* A3      = A1 + (size_t)4096 * 512;         // 4096x768 (stage2 overlay)
    unsigned short* Hb      = A1;                              // 4096x1024 (stage3 overlay)
    unsigned short* KN      = A1 + (size_t)4096 * 1280;        // 4096x256 knn_out (CC+256 view)
    unsigned short* CC      = KN;                              // 4096x512 [proj_out | knn_out]
    unsigned short* XB      = CC + (size_t)4096 * 512;         // 4096x256 LN out
    unsigned short* NVB     = XB + (size_t)4096 * 256;         // 4096x256 LN(v)
    unsigned short* WT      = NVB + (size_t)4096 * 256;        // weights, 1572864 us
    unsigned short* WT1     = WT;
    unsigned short* WTproj  = WT + 327680;
    unsigned short* WTmerge = WT + 393216;
    unsigned short* WT2     = WT + 524288;
    unsigned short* WT3     = WT + 655360;
    unsigned short* WTprojx = WT + 851968;
    unsigned short* WTmergex= WT + 917504;
    unsigned short* WTfc1   = WT + 1048576;
    unsigned short* WTfc2   = WT + 1310720;
    unsigned short* Opart   = WT + 1572864;                    // [2][4096][256] bf16
    float* Lpart = (float*)(Opart + (size_t)2 * 4096 * 256);   // [2][4096][8]  f32

    dim3 blk(256), blk8(512);
    dim3 gAG(NQC / 64, 8, 8);     // z<4: attn (b*2+ck); z>=4: gather

    // prep weights + stage-1 LN (packed)
    prep_ln<<<dim3(2560), blk, 0, stream>>>(sa_qkv_w, knn_w, sa_proj_w, merge_w,
        ca_q_w, knnx_w, ca_kv_w, ca_proj_w, mergex_w, fc1_w, fc2_w, WT,
        q_in, n1g, n1b, XB);

    // ---- stage 1 ----
    gemm64<0,0,1><<<dim3(20,64), blk, 0, stream>>>(XB, 256, WT1,
        nullptr, nullptr, 0, A1, 1280, 256);                                        // [qkv|P|Base]
    attn_gather<<<gAG, blk, 0, stream>>>(A1, 1280, A1+256, 1280, A1+512, 1280,
        Opart, Lpart, A1+768, 1280, A1+1024, 1280, knn_b, idx_s, CC+256, 512);
    gemm64_comb<<<dim3(4,64), blk, 0, stream>>>(Opart, Lpart, WTproj,
        sa_proj_b, CC, 512);                                                        // sa_out (comb fused)
    gemm64x8<0,1,0><<<dim3(4,64), blk8, 0, stream>>>(CC, 512, WTmerge,
        merge_b, q_in, 256, out, 256, 512);                                         // q = q + merge

    // ---- stage 2 ----
    ln2_b<<<dim3(2048), blk, 0, stream>>>(out, nqg, nqb, XB,
        v_in, nvg, nvb, NVB);                                                       // nq2 + nv
    gemm64_dual<<<dim3(20,64), blk, 0, stream>>>(XB, NVB, WT2, WT3, A2, A3);        // both projections
    attn_gather<<<gAG, blk, 0, stream>>>(A2, 512, A3, 768, A3+256, 768,
        Opart, Lpart, A3+512, 768, A2+256, 512, knnx_b, idx_x, CC+256, 512);
    gemm64_comb<<<dim3(4,64), blk, 0, stream>>>(Opart, Lpart, WTprojx,
        ca_proj_b, CC, 512);                                                        // ca_out (comb fused)
    gemm64x8<0,1,0><<<dim3(4,64), blk8, 0, stream>>>(CC, 512, WTmergex,
        mergex_b, out, 256, out, 256, 512);                                         // q = q + mergex

    // ---- stage 3 ----
    ln_b<<<dim3(1024), blk, 0, stream>>>(out, n2g, n2b, XB);                        // h = LN(q)
    gemm64<1,0,1><<<dim3(16,64), blk, 0, stream>>>(XB, 256, WTfc1,
        fc1_b, nullptr, 0, Hb, 1024, 256);                                          // gelu(LN(q)@fc1+b)
    gemm64x8<0,1,0><<<dim3(4,64), blk8, 0, stream>>>(Hb, 1024, WTfc2,
        fc2_b, out, 256, out, 256, 1024);                                           // q += fc2
}